// Round 3
// baseline (475.444 us; speedup 1.0000x reference)
//
#include <hip/hip_runtime.h>

#define RR    80      // max radius (TRUNCATE * MAX_SIGMA + 0.5)
#define WDIM  256     // H == W == 256
#define NSAMP 512
#define BH    32      // output rows per block along blur axis
#define UCH   8       // tap chunk (weights kept in registers)
#define CHPS  (WDIM / BH)   // chunks per sample = 8

typedef float f32x4 __attribute__((ext_vector_type(4)));

__device__ __forceinline__ int reflect(int q) {
    // symmetric padding, single reflection valid (max overshoot < WDIM)
    q = (q < 0) ? (-q - 1) : q;
    return (q >= WDIM) ? (2 * WDIM - 1 - q) : q;
}

// Compute normalized per-sample weights into wl[192] (zero-padded outside [0,160]).
// Returns radius. Must be called by all 256 threads (contains __syncthreads).
__device__ __forceinline__ int make_weights(int b, const float* __restrict__ sigmas,
                                            const int* __restrict__ steps,
                                            float* wl, float* red) {
    int t = threadIdx.x;
    float sigma = sigmas[steps[b]];
    float radf = floorf(4.0f * sigma + 0.5f);
    if (t < 192) {
        float w = 0.0f;
        if (t < 161) {
            float off = (float)(t - RR);
            if (fabsf(off) <= radf) {
                float z = off / sigma;
                w = expf(-0.5f * z * z);
            }
        }
        wl[t] = w;
    }
    __syncthreads();
    if (t < 64) {
        float s = wl[t] + wl[t + 64] + wl[t + 128];
        #pragma unroll
        for (int o = 32; o > 0; o >>= 1) s += __shfl_down(s, o);
        if (t == 0) red[0] = 1.0f / s;
    }
    __syncthreads();
    float rs = red[0];
    if (t < 161) wl[t] *= rs;
    __syncthreads();
    return (int)radf;
}

// Blur along the second-to-last index of in[b][r][c]; if TOUT, write out[b][c][r]
// (transposed). Applying the TOUT version twice gives horizontal(vertical(x)).
template <bool TOUT>
__global__ __launch_bounds__(256) void vblur(const float* __restrict__ in,
                                             float* __restrict__ out,
                                             const float* __restrict__ sigmas,
                                             const int* __restrict__ steps) {
    __shared__ float wl[192];
    __shared__ float red[1];

    // XCD-aware swizzle: grid = NSAMP*CHPS = 4096 (divisible by 8 XCDs).
    // Give each XCD a contiguous range of samples so all CHPS chunks of a
    // sample hit the same per-XCD L2 (sample slice + halo << 4 MiB).
    int bid = blockIdx.x;
    int sw  = (bid & 7) * (NSAMP * CHPS / 8) + (bid >> 3);
    int b   = sw / CHPS;
    int i0  = (sw % CHPS) * BH;

    int rad = make_weights(b, sigmas, steps, wl, red);
    int j = threadIdx.x;
    const float* inb = in + (size_t)b * WDIM * WDIM;

    float acc[BH];
    #pragma unroll
    for (int ii = 0; ii < BH; ++ii) acc[ii] = 0.0f;

    int nc = (2 * rad + UCH) / UCH;   // ceil((2*rad+1)/UCH)
    int ubase = -rad;
    for (int c = 0; c < nc; ++c, ubase += UCH) {
        float wreg[UCH];
        #pragma unroll
        for (int t = 0; t < UCH; ++t) wreg[t] = wl[RR + ubase + t];  // broadcast reads
        float vwin[BH + UCH - 1];
        #pragma unroll
        for (int s = 0; s < BH + UCH - 1; ++s) {
            int rr = reflect(i0 + ubase + s);
            vwin[s] = inb[rr * WDIM + j];   // coalesced across lanes
        }
        #pragma unroll
        for (int ii = 0; ii < BH; ++ii) {
            #pragma unroll
            for (int t = 0; t < UCH; ++t)
                acc[ii] = fmaf(wreg[t], vwin[ii + t], acc[ii]);
        }
    }

    if (TOUT) {
        // thread j writes BH contiguous floats of output row j (128 B)
        float* ob = out + ((size_t)b * WDIM + j) * WDIM + i0;
        #pragma unroll
        for (int q = 0; q < BH / 4; ++q) {
            f32x4 v;
            v.x = acc[4 * q]; v.y = acc[4 * q + 1];
            v.z = acc[4 * q + 2]; v.w = acc[4 * q + 3];
            __builtin_nontemporal_store(v, (f32x4*)(ob + 4 * q));
        }
    } else {
        #pragma unroll
        for (int ii = 0; ii < BH; ++ii)
            out[((size_t)b * WDIM + (i0 + ii)) * WDIM + j] = acc[ii];
    }
}

// Fallback horizontal pass (in-place, row-local): only used if ws_size too small.
__global__ __launch_bounds__(256) void hblur_inplace(float* __restrict__ buf,
                                                     const float* __restrict__ sigmas,
                                                     const int* __restrict__ steps) {
    __shared__ float wl[192];
    __shared__ float red[1];
    __shared__ float rp[WDIM + 2 * RR];
    int bid = blockIdx.x;
    int b = bid >> 8;
    int i = bid & 255;
    float* row = buf + ((size_t)b * WDIM + i) * WDIM;
    int t = threadIdx.x;
    for (int s = t; s < WDIM + 2 * RR; s += 256) rp[s] = row[reflect(s - RR)];
    int rad = make_weights(b, sigmas, steps, wl, red);  // includes __syncthreads
    float acc = 0.0f;
    for (int u = -rad; u <= rad; ++u) acc = fmaf(wl[RR + u], rp[RR + t + u], acc);
    row[t] = acc;
}

extern "C" void kernel_launch(void* const* d_in, const int* in_sizes, int n_in,
                              void* d_out, int out_size, void* d_ws, size_t ws_size,
                              hipStream_t stream) {
    const float* x     = (const float*)d_in[0];
    const float* sig   = (const float*)d_in[1];
    const int*   steps = (const int*)d_in[2];
    float* out = (float*)d_out;

    const size_t tmp_bytes = (size_t)NSAMP * WDIM * WDIM * sizeof(float);
    const int nblk = NSAMP * CHPS;   // 4096

    if (ws_size >= tmp_bytes) {
        float* tmp = (float*)d_ws;
        vblur<true><<<nblk, 256, 0, stream>>>(x, tmp, sig, steps);
        vblur<true><<<nblk, 256, 0, stream>>>(tmp, out, sig, steps);
    } else {
        vblur<false><<<nblk, 256, 0, stream>>>(x, out, sig, steps);
        hblur_inplace<<<NSAMP * WDIM, 256, 0, stream>>>(out, sig, steps);
    }
}

// Round 4
// 379.969 us; speedup vs baseline: 1.2513x; 1.2513x over previous
//
#include <hip/hip_runtime.h>

#define RR    80      // max radius (TRUNCATE * MAX_SIGMA + 0.5)
#define WDIM  256     // H == W == 256
#define NSAMP 512
#define BH    8       // output rows per WAVE
#define UCH   8       // tap chunk (weights kept in registers)
#define BPS   8       // blocks per sample (4 waves * BH = 32 rows per block)
#define NBLK  (NSAMP * BPS)   // 4096, divisible by 8 XCDs

typedef float f32x4 __attribute__((ext_vector_type(4)));

__device__ __forceinline__ int reflect(int q) {
    q = (q < 0) ? (-q - 1) : q;
    return (q >= WDIM) ? (2 * WDIM - 1 - q) : q;
}

// Normalized per-sample weights into wl[192] (zero outside [0,160]). Returns radius.
// Must be called by all 256 threads (contains __syncthreads).
__device__ __forceinline__ int make_weights(int b, const float* __restrict__ sigmas,
                                            const int* __restrict__ steps,
                                            float* wl, float* red) {
    int t = threadIdx.x;
    float sigma = sigmas[steps[b]];
    float radf = floorf(4.0f * sigma + 0.5f);
    if (t < 192) {
        float w = 0.0f;
        if (t < 161) {
            float off = (float)(t - RR);
            if (fabsf(off) <= radf) {
                float z = off / sigma;
                w = expf(-0.5f * z * z);
            }
        }
        wl[t] = w;
    }
    __syncthreads();
    if (t < 64) {
        float s = wl[t] + wl[t + 64] + wl[t + 128];
        #pragma unroll
        for (int o = 32; o > 0; o >>= 1) s += __shfl_down(s, o);
        if (t == 0) red[0] = 1.0f / s;
    }
    __syncthreads();
    float rs = red[0];
    if (t < 161) wl[t] *= rs;
    __syncthreads();
    return (int)radf;
}

// Row-wise vertical blur, float4 per lane (one wave-load = one full 1KB row).
// Each wave owns BH=8 output rows; writes output transposed: out[b][c][r].
// Applying twice (x -> tmp -> out) gives horizontal(vertical(x)) unrotated.
__global__ __launch_bounds__(256, 4) void vblur4(const float* __restrict__ in,
                                                 float* __restrict__ out,
                                                 const float* __restrict__ sigmas,
                                                 const int* __restrict__ steps) {
    __shared__ float wl[192];
    __shared__ float red[1];

    // XCD swizzle: XCD k gets contiguous sw range -> samples [k*64,(k+1)*64),
    // so all 8 blocks of a sample share one per-XCD L2.
    int bid = blockIdx.x;
    int sw  = (bid & 7) * (NBLK / 8) + (bid >> 3);
    int b   = sw / BPS;
    int r0b = (sw % BPS) * (4 * BH);

    int rad = make_weights(b, sigmas, steps, wl, red);

    int wv = threadIdx.x >> 6;        // wave 0..3
    int ln = threadIdx.x & 63;        // lane
    int r0 = r0b + wv * BH;           // this wave's first output row
    const float* inb = in + (size_t)b * WDIM * WDIM;

    f32x4 acc[BH];
    #pragma unroll
    for (int ii = 0; ii < BH; ++ii) acc[ii] = (f32x4)0.0f;

    int nc = (2 * rad + UCH) / UCH;   // ceil((2*rad+1)/UCH)
    int ubase = -rad;
    for (int c = 0; c < nc; ++c, ubase += UCH) {
        float wreg[UCH];
        #pragma unroll
        for (int t = 0; t < UCH; ++t) wreg[t] = wl[RR + ubase + t];  // LDS broadcast
        f32x4 vwin[BH + UCH - 1];
        #pragma unroll
        for (int s = 0; s < BH + UCH - 1; ++s) {
            int rr = reflect(r0 + ubase + s);
            vwin[s] = *(const f32x4*)(inb + rr * WDIM + 4 * ln);  // 1KB/wave, coalesced
        }
        #pragma unroll
        for (int ii = 0; ii < BH; ++ii) {
            #pragma unroll
            for (int t = 0; t < UCH; ++t)
                acc[ii] += wreg[t] * vwin[ii + t];
        }
    }

    // Transposed store: lane handles output rows (cols in input space) 4ln..4ln+3.
    float* ob = out + (size_t)b * WDIM * WDIM + (size_t)(4 * ln) * WDIM + r0;
    #pragma unroll
    for (int k = 0; k < 4; ++k) {
        f32x4 v0, v1;
        v0.x = acc[0][k]; v0.y = acc[1][k]; v0.z = acc[2][k]; v0.w = acc[3][k];
        v1.x = acc[4][k]; v1.y = acc[5][k]; v1.z = acc[6][k]; v1.w = acc[7][k];
        *(f32x4*)(ob + k * WDIM)     = v0;
        *(f32x4*)(ob + k * WDIM + 4) = v1;
    }
}

// ---------- fallback path (only if ws_size too small for the 134MB tmp) ----------
__global__ __launch_bounds__(256) void vblur_nt(const float* __restrict__ in,
                                                float* __restrict__ out,
                                                const float* __restrict__ sigmas,
                                                const int* __restrict__ steps) {
    __shared__ float wl[192];
    __shared__ float red[1];
    int bid = blockIdx.x;
    int b   = bid >> 4;
    int i0  = (bid & 15) * 16;
    int rad = make_weights(b, sigmas, steps, wl, red);
    int j = threadIdx.x;
    const float* inb = in + (size_t)b * WDIM * WDIM;
    float acc[16];
    #pragma unroll
    for (int ii = 0; ii < 16; ++ii) acc[ii] = 0.0f;
    for (int u = -rad; u <= rad; ++u) {
        float w = wl[RR + u];
        #pragma unroll
        for (int ii = 0; ii < 16; ++ii)
            acc[ii] = fmaf(w, inb[reflect(i0 + ii + u) * WDIM + j], acc[ii]);
    }
    #pragma unroll
    for (int ii = 0; ii < 16; ++ii)
        out[((size_t)b * WDIM + (i0 + ii)) * WDIM + j] = acc[ii];
}

__global__ __launch_bounds__(256) void hblur_inplace(float* __restrict__ buf,
                                                     const float* __restrict__ sigmas,
                                                     const int* __restrict__ steps) {
    __shared__ float wl[192];
    __shared__ float red[1];
    __shared__ float rp[WDIM + 2 * RR];
    int bid = blockIdx.x;
    int b = bid >> 8;
    int i = bid & 255;
    float* row = buf + ((size_t)b * WDIM + i) * WDIM;
    int t = threadIdx.x;
    for (int s = t; s < WDIM + 2 * RR; s += 256) rp[s] = row[reflect(s - RR)];
    int rad = make_weights(b, sigmas, steps, wl, red);
    float acc = 0.0f;
    for (int u = -rad; u <= rad; ++u) acc = fmaf(wl[RR + u], rp[RR + t + u], acc);
    row[t] = acc;
}
// ----------------------------------------------------------------------------------

extern "C" void kernel_launch(void* const* d_in, const int* in_sizes, int n_in,
                              void* d_out, int out_size, void* d_ws, size_t ws_size,
                              hipStream_t stream) {
    const float* x     = (const float*)d_in[0];
    const float* sig   = (const float*)d_in[1];
    const int*   steps = (const int*)d_in[2];
    float* out = (float*)d_out;

    const size_t tmp_bytes = (size_t)NSAMP * WDIM * WDIM * sizeof(float);

    if (ws_size >= tmp_bytes) {
        float* tmp = (float*)d_ws;
        vblur4<<<NBLK, 256, 0, stream>>>(x, tmp, sig, steps);
        vblur4<<<NBLK, 256, 0, stream>>>(tmp, out, sig, steps);
    } else {
        vblur_nt<<<NSAMP * 16, 256, 0, stream>>>(x, out, sig, steps);
        hblur_inplace<<<NSAMP * WDIM, 256, 0, stream>>>(out, sig, steps);
    }
}

// Round 5
// 233.897 us; speedup vs baseline: 2.0327x; 1.6245x over previous
//
#include <hip/hip_runtime.h>

#define RR    80      // max radius (TRUNCATE * MAX_SIGMA + 0.5)
#define WDIM  256     // H == W == 256
#define NSAMP 512
#define BH    32      // output rows per block (full-width rows, scalar threads)
#define UCH   8       // tap chunk (weights kept in registers)
#define CHPS  (WDIM / BH)     // 8 chunks per sample
#define NBLK  (NSAMP * CHPS)  // 4096, divisible by 8 XCDs

typedef float     f32x4 __attribute__((ext_vector_type(4)));
typedef _Float16  f16x8 __attribute__((ext_vector_type(8)));

__device__ __forceinline__ int reflect(int q) {
    q = (q < 0) ? (-q - 1) : q;
    return (q >= WDIM) ? (2 * WDIM - 1 - q) : q;
}

// Normalized per-sample weights into wl[192] (zero outside [0,160]). Returns radius.
// Must be called by all 256 threads (contains __syncthreads).
__device__ __forceinline__ int make_weights(int b, const float* __restrict__ sigmas,
                                            const int* __restrict__ steps,
                                            float* wl, float* red) {
    int t = threadIdx.x;
    float sigma = sigmas[steps[b]];
    float radf = floorf(4.0f * sigma + 0.5f);
    if (t < 192) {
        float w = 0.0f;
        if (t < 161) {
            float off = (float)(t - RR);
            if (fabsf(off) <= radf) {
                float z = off / sigma;
                w = expf(-0.5f * z * z);
            }
        }
        wl[t] = w;
    }
    __syncthreads();
    if (t < 64) {
        float s = wl[t] + wl[t + 64] + wl[t + 128];
        #pragma unroll
        for (int o = 32; o > 0; o >>= 1) s += __shfl_down(s, o);
        if (t == 0) red[0] = 1.0f / s;
    }
    __syncthreads();
    float rs = red[0];
    if (t < 161) wl[t] *= rs;
    __syncthreads();
    return (int)radf;
}

// Vertical blur along rows of in[b][r][c]; writes transposed out[b][c][r].
// Thread j = one column; block = BH=32 contiguous output rows (block-wide
// shared halo window -> best L2 dedup, measured FETCH 196MB in r3).
// Applying twice (x -> tmp(fp16) -> out) gives horizontal(vertical(x)).
template <typename TI, typename TO>
__global__ __launch_bounds__(256) void vblur_t(const TI* __restrict__ in,
                                               TO* __restrict__ out,
                                               const float* __restrict__ sigmas,
                                               const int* __restrict__ steps) {
    __shared__ float wl[192];
    __shared__ float red[1];

    // XCD swizzle: XCD k gets samples [64k, 64(k+1)) so a sample's 8 blocks
    // share one per-XCD L2.
    int bid = blockIdx.x;
    int sw  = (bid & 7) * (NBLK / 8) + (bid >> 3);
    int b   = sw / CHPS;
    int i0  = (sw % CHPS) * BH;

    int rad = make_weights(b, sigmas, steps, wl, red);
    int j = threadIdx.x;
    const TI* inb = in + (size_t)b * WDIM * WDIM;

    float acc[BH];
    #pragma unroll
    for (int ii = 0; ii < BH; ++ii) acc[ii] = 0.0f;

    int nc = (2 * rad + UCH) / UCH;   // ceil((2*rad+1)/UCH)
    int ubase = -rad;
    for (int c = 0; c < nc; ++c, ubase += UCH) {
        float wreg[UCH];
        #pragma unroll
        for (int t = 0; t < UCH; ++t) wreg[t] = wl[RR + ubase + t];  // LDS broadcast
        float vwin[BH + UCH - 1];
        #pragma unroll
        for (int s = 0; s < BH + UCH - 1; ++s) {
            int rr = reflect(i0 + ubase + s);
            vwin[s] = (float)inb[rr * WDIM + j];   // coalesced across lanes
        }
        #pragma unroll
        for (int ii = 0; ii < BH; ++ii) {
            #pragma unroll
            for (int t = 0; t < UCH; ++t)
                acc[ii] = fmaf(wreg[t], vwin[ii + t], acc[ii]);
        }
    }

    // Transposed store: thread j owns output row j, writes BH contiguous elems.
    // fp16: 64B (one full line); fp32: 128B (two full lines) -> no partial lines.
    TO* ob = out + ((size_t)b * WDIM + j) * WDIM + i0;
    if constexpr (sizeof(TO) == 2) {
        #pragma unroll
        for (int q = 0; q < BH / 8; ++q) {
            f16x8 v;
            #pragma unroll
            for (int t = 0; t < 8; ++t) v[t] = (_Float16)acc[8 * q + t];
            *(f16x8*)(ob + 8 * q) = v;
        }
    } else {
        #pragma unroll
        for (int q = 0; q < BH / 4; ++q) {
            f32x4 v;
            v.x = acc[4 * q]; v.y = acc[4 * q + 1];
            v.z = acc[4 * q + 2]; v.w = acc[4 * q + 3];
            *(f32x4*)(ob + 4 * q) = v;
        }
    }
}

// ---------- fallback path (only if ws_size too small for the 67MB fp16 tmp) ----------
__global__ __launch_bounds__(256) void vblur_nt(const float* __restrict__ in,
                                                float* __restrict__ out,
                                                const float* __restrict__ sigmas,
                                                const int* __restrict__ steps) {
    __shared__ float wl[192];
    __shared__ float red[1];
    int bid = blockIdx.x;
    int b   = bid >> 4;
    int i0  = (bid & 15) * 16;
    int rad = make_weights(b, sigmas, steps, wl, red);
    int j = threadIdx.x;
    const float* inb = in + (size_t)b * WDIM * WDIM;
    float acc[16];
    #pragma unroll
    for (int ii = 0; ii < 16; ++ii) acc[ii] = 0.0f;
    for (int u = -rad; u <= rad; ++u) {
        float w = wl[RR + u];
        #pragma unroll
        for (int ii = 0; ii < 16; ++ii)
            acc[ii] = fmaf(w, inb[reflect(i0 + ii + u) * WDIM + j], acc[ii]);
    }
    #pragma unroll
    for (int ii = 0; ii < 16; ++ii)
        out[((size_t)b * WDIM + (i0 + ii)) * WDIM + j] = acc[ii];
}

__global__ __launch_bounds__(256) void hblur_inplace(float* __restrict__ buf,
                                                     const float* __restrict__ sigmas,
                                                     const int* __restrict__ steps) {
    __shared__ float wl[192];
    __shared__ float red[1];
    __shared__ float rp[WDIM + 2 * RR];
    int bid = blockIdx.x;
    int b = bid >> 8;
    int i = bid & 255;
    float* row = buf + ((size_t)b * WDIM + i) * WDIM;
    int t = threadIdx.x;
    for (int s = t; s < WDIM + 2 * RR; s += 256) rp[s] = row[reflect(s - RR)];
    int rad = make_weights(b, sigmas, steps, wl, red);
    float acc = 0.0f;
    for (int u = -rad; u <= rad; ++u) acc = fmaf(wl[RR + u], rp[RR + t + u], acc);
    row[t] = acc;
}
// --------------------------------------------------------------------------------------

extern "C" void kernel_launch(void* const* d_in, const int* in_sizes, int n_in,
                              void* d_out, int out_size, void* d_ws, size_t ws_size,
                              hipStream_t stream) {
    const float* x     = (const float*)d_in[0];
    const float* sig   = (const float*)d_in[1];
    const int*   steps = (const int*)d_in[2];
    float* out = (float*)d_out;

    const size_t tmp_bytes = (size_t)NSAMP * WDIM * WDIM * sizeof(_Float16);

    if (ws_size >= tmp_bytes) {
        _Float16* tmp = (_Float16*)d_ws;
        vblur_t<float, _Float16><<<NBLK, 256, 0, stream>>>(x, tmp, sig, steps);
        vblur_t<_Float16, float><<<NBLK, 256, 0, stream>>>(tmp, out, sig, steps);
    } else {
        vblur_nt<<<NSAMP * 16, 256, 0, stream>>>(x, out, sig, steps);
        hblur_inplace<<<NSAMP * WDIM, 256, 0, stream>>>(out, sig, steps);
    }
}

// Round 6
// 183.230 us; speedup vs baseline: 2.5948x; 1.2765x over previous
//
#include <hip/hip_runtime.h>

#define RR    80      // max radius (TRUNCATE * MAX_SIGMA + 0.5)
#define WDIM  256     // H == W == 256
#define NSAMP 512
#define BH    32      // rows per block
#define WH    8       // rows per wave
#define UCH   8       // tap chunk
#define NR    48      // LDS ring rows (window 39 + 8 in flight <= 48)
#define CHPS  (WDIM / BH)     // 8
#define NBLK  (NSAMP * CHPS)  // 4096

typedef float     f32x4 __attribute__((ext_vector_type(4)));
typedef _Float16  f16x4 __attribute__((ext_vector_type(4)));
typedef _Float16  f16x8 __attribute__((ext_vector_type(8)));

__device__ __forceinline__ int reflect(int q) {
    q = (q < 0) ? (-q - 1) : q;
    return (q >= WDIM) ? (2 * WDIM - 1 - q) : q;
}

template <typename TI>
__device__ __forceinline__ f32x4 load_row4(const TI* __restrict__ base, int row, int ln) {
    if constexpr (sizeof(TI) == 2) {
        f16x4 h = *(const f16x4*)(base + (size_t)row * WDIM + 4 * ln);
        f32x4 v;
        v[0] = (float)h[0]; v[1] = (float)h[1]; v[2] = (float)h[2]; v[3] = (float)h[3];
        return v;
    } else {
        return *(const f32x4*)(base + (size_t)row * WDIM + 4 * ln);
    }
}

// Normalized per-sample weights into wl[192] (zero outside mask). Returns radius.
__device__ __forceinline__ int make_weights(int b, const float* __restrict__ sigmas,
                                            const int* __restrict__ steps,
                                            float* wl, float* red) {
    int t = threadIdx.x;
    float sigma = sigmas[steps[b]];
    float radf = floorf(4.0f * sigma + 0.5f);
    if (t < 192) {
        float w = 0.0f;
        if (t < 161) {
            float off = (float)(t - RR);
            if (fabsf(off) <= radf) {
                float z = off / sigma;
                w = expf(-0.5f * z * z);
            }
        }
        wl[t] = w;
    }
    __syncthreads();
    if (t < 64) {
        float s = wl[t] + wl[t + 64] + wl[t + 128];
        #pragma unroll
        for (int o = 32; o > 0; o >>= 1) s += __shfl_down(s, o);
        if (t == 0) red[0] = 1.0f / s;
    }
    __syncthreads();
    float rs = red[0];
    if (t < 161) wl[t] *= rs;
    __syncthreads();
    return (int)radf;
}

// Vertical blur with LDS ring-buffer sliding window; writes transposed out[b][c][r].
// 4 waves/block; wave wv owns output rows i0+8wv..+7, lane ln owns cols 4ln..4ln+3.
template <typename TI, typename TO>
__global__ __launch_bounds__(256) void vblur_ring(const TI* __restrict__ in,
                                                  TO* __restrict__ out,
                                                  const float* __restrict__ sigmas,
                                                  const int* __restrict__ steps) {
    __shared__ float ring[NR][WDIM];
    __shared__ float wl[192];
    __shared__ float red[1];

    // XCD swizzle: a sample's 8 blocks share one per-XCD L2.
    int bid = blockIdx.x;
    int sw  = (bid & 7) * (NBLK / 8) + (bid >> 3);
    int b   = sw / CHPS;
    int i0  = (sw % CHPS) * BH;

    int rad = make_weights(b, sigmas, steps, wl, red);
    int nc  = (2 * rad + UCH) / UCH;        // chunks
    int relmax = 8 * nc + 30;               // last referenced window row (rel)

    int wv = threadIdx.x >> 6;
    int ln = threadIdx.x & 63;
    const TI* inb = in + (size_t)b * WDIM * WDIM;
    int base = i0 - rad;                    // rel 0 -> absolute row

    // Prologue: stage rel rows [0, 39) cooperatively (wave wv takes wv+4k).
    {
        f32x4 pv[10];
        #pragma unroll
        for (int k = 0; k < 10; ++k) {
            int rel = wv + 4 * k;
            if (rel < 39) pv[k] = load_row4(inb, reflect(base + rel), ln);
        }
        #pragma unroll
        for (int k = 0; k < 10; ++k) {
            int rel = wv + 4 * k;
            if (rel < 39) *(f32x4*)&ring[rel][4 * ln] = pv[k];
        }
        __syncthreads();
    }

    f32x4 acc[WH];
    #pragma unroll
    for (int ii = 0; ii < WH; ++ii) acc[ii] = (f32x4)0.0f;

    for (int c = 0; c < nc; ++c) {
        // (1) issue next-window staging loads early (T14: latency hides under FMA)
        f32x4 sv[2];
        int   srel[2];
        #pragma unroll
        for (int k = 0; k < 2; ++k) {
            int rel = 39 + 8 * c + 2 * wv + k;
            srel[k] = rel;
            if (rel <= relmax) sv[k] = load_row4(inb, reflect(base + rel), ln);
        }
        // (2) weights (LDS broadcast)
        float wreg[UCH];
        #pragma unroll
        for (int t = 0; t < UCH; ++t) wreg[t] = wl[RR - rad + 8 * c + t];
        // (3) window from LDS ring
        f32x4 w15[WH + UCH - 1];
        int s0 = (8 * c + 8 * wv) % NR;
        #pragma unroll
        for (int s = 0; s < WH + UCH - 1; ++s) {
            int sl = s0 + s; if (sl >= NR) sl -= NR;
            w15[s] = *(const f32x4*)&ring[sl][4 * ln];
        }
        // (4) FMA
        #pragma unroll
        for (int ii = 0; ii < WH; ++ii) {
            #pragma unroll
            for (int t = 0; t < UCH; ++t)
                acc[ii] += wreg[t] * w15[ii + t];
        }
        // (5) commit staged rows (slots disjoint from this chunk's read set)
        #pragma unroll
        for (int k = 0; k < 2; ++k) {
            if (srel[k] <= relmax) {
                int sl = srel[k] % NR;
                *(f32x4*)&ring[sl][4 * ln] = sv[k];
            }
        }
        __syncthreads();
    }

    // Transposed store: lane ln, k in 0..3 -> output row (col) 4ln+k,
    // contiguous 8 elems at i0+8wv (f16: 16B, f32: 2x16B, aligned).
    if constexpr (sizeof(TO) == 2) {
        TO* ob = out + (size_t)b * WDIM * WDIM;
        #pragma unroll
        for (int k = 0; k < 4; ++k) {
            f16x8 v;
            #pragma unroll
            for (int ii = 0; ii < 8; ++ii) v[ii] = (_Float16)acc[ii][k];
            *(f16x8*)(ob + (size_t)(4 * ln + k) * WDIM + i0 + 8 * wv) = v;
        }
    } else {
        float* ob = (float*)out + (size_t)b * WDIM * WDIM;
        #pragma unroll
        for (int k = 0; k < 4; ++k) {
            f32x4 v0, v1;
            v0[0] = acc[0][k]; v0[1] = acc[1][k]; v0[2] = acc[2][k]; v0[3] = acc[3][k];
            v1[0] = acc[4][k]; v1[1] = acc[5][k]; v1[2] = acc[6][k]; v1[3] = acc[7][k];
            *(f32x4*)(ob + (size_t)(4 * ln + k) * WDIM + i0 + 8 * wv)     = v0;
            *(f32x4*)(ob + (size_t)(4 * ln + k) * WDIM + i0 + 8 * wv + 4) = v1;
        }
    }
}

// ---------- fallback path (only if ws too small for the 67MB fp16 tmp) ----------
__global__ __launch_bounds__(256) void vblur_nt(const float* __restrict__ in,
                                                float* __restrict__ out,
                                                const float* __restrict__ sigmas,
                                                const int* __restrict__ steps) {
    __shared__ float wl[192];
    __shared__ float red[1];
    int bid = blockIdx.x;
    int b   = bid >> 4;
    int i0  = (bid & 15) * 16;
    int rad = make_weights(b, sigmas, steps, wl, red);
    int j = threadIdx.x;
    const float* inb = in + (size_t)b * WDIM * WDIM;
    float acc[16];
    #pragma unroll
    for (int ii = 0; ii < 16; ++ii) acc[ii] = 0.0f;
    for (int u = -rad; u <= rad; ++u) {
        float w = wl[RR + u];
        #pragma unroll
        for (int ii = 0; ii < 16; ++ii)
            acc[ii] = fmaf(w, inb[reflect(i0 + ii + u) * WDIM + j], acc[ii]);
    }
    #pragma unroll
    for (int ii = 0; ii < 16; ++ii)
        out[((size_t)b * WDIM + (i0 + ii)) * WDIM + j] = acc[ii];
}

__global__ __launch_bounds__(256) void hblur_inplace(float* __restrict__ buf,
                                                     const float* __restrict__ sigmas,
                                                     const int* __restrict__ steps) {
    __shared__ float wl[192];
    __shared__ float red[1];
    __shared__ float rp[WDIM + 2 * RR];
    int bid = blockIdx.x;
    int b = bid >> 8;
    int i = bid & 255;
    float* row = buf + ((size_t)b * WDIM + i) * WDIM;
    int t = threadIdx.x;
    for (int s = t; s < WDIM + 2 * RR; s += 256) rp[s] = row[reflect(s - RR)];
    int rad = make_weights(b, sigmas, steps, wl, red);
    float acc = 0.0f;
    for (int u = -rad; u <= rad; ++u) acc = fmaf(wl[RR + u], rp[RR + t + u], acc);
    row[t] = acc;
}
// --------------------------------------------------------------------------------

extern "C" void kernel_launch(void* const* d_in, const int* in_sizes, int n_in,
                              void* d_out, int out_size, void* d_ws, size_t ws_size,
                              hipStream_t stream) {
    const float* x     = (const float*)d_in[0];
    const float* sig   = (const float*)d_in[1];
    const int*   steps = (const int*)d_in[2];
    float* out = (float*)d_out;

    const size_t tmp_bytes = (size_t)NSAMP * WDIM * WDIM * sizeof(_Float16);

    if (ws_size >= tmp_bytes) {
        _Float16* tmp = (_Float16*)d_ws;
        vblur_ring<float, _Float16><<<NBLK, 256, 0, stream>>>(x, tmp, sig, steps);
        vblur_ring<_Float16, float><<<NBLK, 256, 0, stream>>>(tmp, out, sig, steps);
    } else {
        vblur_nt<<<NSAMP * 16, 256, 0, stream>>>(x, out, sig, steps);
        hblur_inplace<<<NSAMP * WDIM, 256, 0, stream>>>(out, sig, steps);
    }
}

// Round 8
// 170.617 us; speedup vs baseline: 2.7866x; 1.0739x over previous
//
#include <hip/hip_runtime.h>

#define RR    80      // max radius (TRUNCATE * MAX_SIGMA + 0.5)
#define WDIM  256     // H == W == 256
#define NSAMP 512
#define BH    32      // rows per block
#define WH    8       // rows per wave
#define UCH   8       // tap chunk
#define NR    48      // LDS ring rows (live span 47 <= 48)
#define CHPS  (WDIM / BH)     // 8
#define NBLK  (NSAMP * CHPS)  // 4096

typedef float     f32x4 __attribute__((ext_vector_type(4)));
typedef _Float16  f16x4 __attribute__((ext_vector_type(4)));
typedef _Float16  f16x8 __attribute__((ext_vector_type(8)));

template <bool B, class A, class C> struct cond_t { using type = A; };
template <class A, class C> struct cond_t<false, A, C> { using type = C; };

__device__ __forceinline__ int reflect(int q) {
    q = (q < 0) ? (-q - 1) : q;
    return (q >= WDIM) ? (2 * WDIM - 1 - q) : q;
}

// Raw (untyped-width) row load: no conversion at issue time, so the compiler's
// vmcnt wait lands at the consumer (ds-commit), not here.
template <typename TI, typename RawT>
__device__ __forceinline__ RawT load_raw(const TI* __restrict__ base, int row, int ln) {
    return *(const RawT*)(base + (size_t)row * WDIM + 4 * ln);
}

__device__ __forceinline__ f32x4 to_f32(f32x4 v) { return v; }
__device__ __forceinline__ f32x4 to_f32(f16x4 h) {
    f32x4 v;
    v[0] = (float)h[0]; v[1] = (float)h[1]; v[2] = (float)h[2]; v[3] = (float)h[3];
    return v;
}

// Normalized per-sample weights into wl[192] (zero outside mask). Returns radius.
__device__ __forceinline__ int make_weights(int b, const float* __restrict__ sigmas,
                                            const int* __restrict__ steps,
                                            float* wl, float* red) {
    int t = threadIdx.x;
    float sigma = sigmas[steps[b]];
    float radf = floorf(4.0f * sigma + 0.5f);
    if (t < 192) {
        float w = 0.0f;
        if (t < 161) {
            float off = (float)(t - RR);
            if (fabsf(off) <= radf) {
                float z = off / sigma;
                w = expf(-0.5f * z * z);
            }
        }
        wl[t] = w;
    }
    __syncthreads();
    if (t < 64) {
        float s = wl[t] + wl[t + 64] + wl[t + 128];
        #pragma unroll
        for (int o = 32; o > 0; o >>= 1) s += __shfl_down(s, o);
        if (t == 0) red[0] = 1.0f / s;
    }
    __syncthreads();
    float rs = red[0];
    if (t < 161) wl[t] *= rs;
    __syncthreads();
    return (int)radf;
}

// Vertical blur, LDS ring (raw input type) with 2-chunk-deep staged pipeline;
// writes transposed out[b][c][r]. 4 waves; wave wv owns rows i0+8wv..+7,
// lane ln owns cols 4ln..4ln+3.
// Pipeline: chunk c reads rels [8c+8wv, 8c+8wv+14] (slots sbb+8wv+s);
// commits rels [8c+39, 8c+46] (slots sbb+39+2wv+k, issued at chunk c-1);
// issues rels [8c+47, 8c+54]. Rel sets mod 48: reads ≡ 8c+{7..38} (+regs 0..6),
// writes ≡ 8c+{39..46} — disjoint.
template <typename TI, typename TO>
__global__ __launch_bounds__(256, 3) void vblur_ring(const TI* __restrict__ in,
                                                     TO* __restrict__ out,
                                                     const float* __restrict__ sigmas,
                                                     const int* __restrict__ steps) {
    using RawT = typename cond_t<sizeof(TI) == 2, f16x4, f32x4>::type;
    __shared__ TI ring[NR][WDIM];
    __shared__ float wl[192];
    __shared__ float red[1];

    // XCD swizzle: a sample's 8 blocks share one per-XCD L2.
    int bid = blockIdx.x;
    int sw  = (bid & 7) * (NBLK / 8) + (bid >> 3);
    int b   = sw / CHPS;
    int i0  = (sw % CHPS) * BH;

    int rad = make_weights(b, sigmas, steps, wl, red);
    int nc  = (2 * rad + UCH) / UCH;        // chunks
    int relmax = 8 * nc + 30;               // last referenced rel row

    int wv = threadIdx.x >> 6;
    int ln = threadIdx.x & 63;
    const TI* inb = in + (size_t)b * WDIM * WDIM;
    int base = i0 - rad;                    // rel 0 -> absolute row

    // Prologue: stage rels [0,39) cooperatively (wave wv takes wv+4k).
    {
        RawT pv[10];
        #pragma unroll
        for (int k = 0; k < 10; ++k) {
            int rel = wv + 4 * k;
            if (rel < 39) pv[k] = load_raw<TI, RawT>(inb, reflect(base + rel), ln);
        }
        #pragma unroll
        for (int k = 0; k < 10; ++k) {
            int rel = wv + 4 * k;
            if (rel < 39) *(RawT*)&ring[rel][4 * ln] = pv[k];
        }
    }
    // Prologue issue: rels [39,46] (committed during chunk 0).
    RawT sv[2];
    #pragma unroll
    for (int k = 0; k < 2; ++k) {
        int rel = 39 + 2 * wv + k;
        if (rel <= relmax) sv[k] = load_raw<TI, RawT>(inb, reflect(base + rel), ln);
    }
    __syncthreads();

    // Sliding window registers: w15[s] <-> rel 8c+8wv+s. Preload s=0..6 for c=0.
    f32x4 w15[WH + UCH - 1];
    #pragma unroll
    for (int s = 0; s < 7; ++s)
        w15[s] = to_f32(*(const RawT*)&ring[8 * wv + s][4 * ln]);

    f32x4 acc[WH];
    #pragma unroll
    for (int ii = 0; ii < WH; ++ii) acc[ii] = (f32x4)0.0f;

    int sbb = 0;   // (8c) mod NR, block-level slot base
    for (int c = 0; c < nc; ++c) {
        // (1) issue loads 2 chunks ahead (latency budget ~= 2 chunks)
        RawT nv[2];
        #pragma unroll
        for (int k = 0; k < 2; ++k) {
            int rel = 47 + 8 * c + 2 * wv + k;
            if (rel <= relmax) nv[k] = load_raw<TI, RawT>(inb, reflect(base + rel), ln);
        }
        // (2) read the 8 new window rows from the ring (s = 7..14)
        #pragma unroll
        for (int s = 7; s < WH + UCH - 1; ++s) {
            int sl = sbb + 8 * wv + s; if (sl >= NR) sl -= NR;   // max 78 -> ok
            w15[s] = to_f32(*(const RawT*)&ring[sl][4 * ln]);
        }
        // (3) weights (LDS broadcast) + FMA
        float wreg[UCH];
        #pragma unroll
        for (int t = 0; t < UCH; ++t) wreg[t] = wl[RR - rad + 8 * c + t];
        #pragma unroll
        for (int ii = 0; ii < WH; ++ii) {
            #pragma unroll
            for (int t = 0; t < UCH; ++t)
                acc[ii] += wreg[t] * w15[ii + t];
        }
        // (4) commit rows issued LAST chunk: rel 39+8c+2wv+k -> slot (sbb+39+2wv+k)%NR
        #pragma unroll
        for (int k = 0; k < 2; ++k) {
            int rel = 39 + 8 * c + 2 * wv + k;
            if (rel <= relmax) {
                int sl = sbb + 39 + 2 * wv + k; if (sl >= NR) sl -= NR;  // max 86 -> ok
                *(RawT*)&ring[sl][4 * ln] = sv[k];
            }
        }
        sv[0] = nv[0]; sv[1] = nv[1];
        // (5) slide the window
        #pragma unroll
        for (int s = 0; s < 7; ++s) w15[s] = w15[s + 8];
        sbb += 8; if (sbb >= NR) sbb -= NR;
        __syncthreads();
    }

    // Transposed store: lane ln, k -> output row 4ln+k, 8 contiguous elems at i0+8wv.
    if constexpr (sizeof(TO) == 2) {
        TO* ob = out + (size_t)b * WDIM * WDIM;
        #pragma unroll
        for (int k = 0; k < 4; ++k) {
            f16x8 v;
            #pragma unroll
            for (int ii = 0; ii < 8; ++ii) v[ii] = (_Float16)acc[ii][k];
            *(f16x8*)(ob + (size_t)(4 * ln + k) * WDIM + i0 + 8 * wv) = v;
        }
    } else {
        float* ob = (float*)out + (size_t)b * WDIM * WDIM;
        #pragma unroll
        for (int k = 0; k < 4; ++k) {
            f32x4 v0, v1;
            v0[0] = acc[0][k]; v0[1] = acc[1][k]; v0[2] = acc[2][k]; v0[3] = acc[3][k];
            v1[0] = acc[4][k]; v1[1] = acc[5][k]; v1[2] = acc[6][k]; v1[3] = acc[7][k];
            *(f32x4*)(ob + (size_t)(4 * ln + k) * WDIM + i0 + 8 * wv)     = v0;
            *(f32x4*)(ob + (size_t)(4 * ln + k) * WDIM + i0 + 8 * wv + 4) = v1;
        }
    }
}

// ---------- fallback path (only if ws too small for the 67MB fp16 tmp) ----------
__global__ __launch_bounds__(256) void vblur_nt(const float* __restrict__ in,
                                                float* __restrict__ out,
                                                const float* __restrict__ sigmas,
                                                const int* __restrict__ steps) {
    __shared__ float wl[192];
    __shared__ float red[1];
    int bid = blockIdx.x;
    int b   = bid >> 4;
    int i0  = (bid & 15) * 16;
    int rad = make_weights(b, sigmas, steps, wl, red);
    int j = threadIdx.x;
    const float* inb = in + (size_t)b * WDIM * WDIM;
    float acc[16];
    #pragma unroll
    for (int ii = 0; ii < 16; ++ii) acc[ii] = 0.0f;
    for (int u = -rad; u <= rad; ++u) {
        float w = wl[RR + u];
        #pragma unroll
        for (int ii = 0; ii < 16; ++ii)
            acc[ii] = fmaf(w, inb[reflect(i0 + ii + u) * WDIM + j], acc[ii]);
    }
    #pragma unroll
    for (int ii = 0; ii < 16; ++ii)
        out[((size_t)b * WDIM + (i0 + ii)) * WDIM + j] = acc[ii];
}

__global__ __launch_bounds__(256) void hblur_inplace(float* __restrict__ buf,
                                                     const float* __restrict__ sigmas,
                                                     const int* __restrict__ steps) {
    __shared__ float wl[192];
    __shared__ float red[1];
    __shared__ float rp[WDIM + 2 * RR];
    int bid = blockIdx.x;
    int b = bid >> 8;
    int i = bid & 255;
    float* row = buf + ((size_t)b * WDIM + i) * WDIM;
    int t = threadIdx.x;
    for (int s = t; s < WDIM + 2 * RR; s += 256) rp[s] = row[reflect(s - RR)];
    int rad = make_weights(b, sigmas, steps, wl, red);
    float acc = 0.0f;
    for (int u = -rad; u <= rad; ++u) acc = fmaf(wl[RR + u], rp[RR + t + u], acc);
    row[t] = acc;
}
// --------------------------------------------------------------------------------

extern "C" void kernel_launch(void* const* d_in, const int* in_sizes, int n_in,
                              void* d_out, int out_size, void* d_ws, size_t ws_size,
                              hipStream_t stream) {
    const float* x     = (const float*)d_in[0];
    const float* sig   = (const float*)d_in[1];
    const int*   steps = (const int*)d_in[2];
    float* out = (float*)d_out;

    const size_t tmp_bytes = (size_t)NSAMP * WDIM * WDIM * sizeof(_Float16);

    if (ws_size >= tmp_bytes) {
        _Float16* tmp = (_Float16*)d_ws;
        vblur_ring<float, _Float16><<<NBLK, 256, 0, stream>>>(x, tmp, sig, steps);
        vblur_ring<_Float16, float><<<NBLK, 256, 0, stream>>>(tmp, out, sig, steps);
    } else {
        vblur_nt<<<NSAMP * 16, 256, 0, stream>>>(x, out, sig, steps);
        hblur_inplace<<<NSAMP * WDIM, 256, 0, stream>>>(out, sig, steps);
    }
}

// Round 9
// 163.841 us; speedup vs baseline: 2.9019x; 1.0414x over previous
//
#include <hip/hip_runtime.h>

#define RR    80      // max radius (TRUNCATE * MAX_SIGMA + 0.5)
#define WDIM  256     // H == W == 256
#define NSAMP 512
#define RB    64      // band rows per block
#define NBND  (WDIM / RB)        // 4 bands per sample
#define NBLK  (NSAMP * NBND)     // 2048 blocks, divisible by 8 XCDs
#define UCH   8       // tap chunk

typedef float    f32x4 __attribute__((ext_vector_type(4)));
typedef _Float16 f16x4 __attribute__((ext_vector_type(4)));
typedef _Float16 f16x8 __attribute__((ext_vector_type(8)));

__device__ __forceinline__ int reflect(int q) {
    // symmetric padding; valid for q in [-WDIM, 2*WDIM)
    q = (q < 0) ? (-q - 1) : q;
    return (q >= WDIM) ? (2 * WDIM - 1 - q) : q;
}

// T tile swizzle: XOR on 16B granules (8 halfs). Depends only on c, so reads
// along i (fixed c) stay contiguous; spreads the transposed v-write across
// all banks. Returns a half-index XOR mask (bits 3..5).
__device__ __forceinline__ int swz(int c) {
    return (((c >> 2) ^ (c >> 5)) & 7) << 3;
}

__device__ __forceinline__ f32x4 h4_to_f32(f16x4 h) {
    f32x4 v;
    v[0] = (float)h[0]; v[1] = (float)h[1]; v[2] = (float)h[2]; v[3] = (float)h[3];
    return v;
}

// Normalized per-sample weights into wl[192] (zero outside mask). Returns radius.
// Must be called by all 256 threads (contains __syncthreads).
__device__ __forceinline__ int make_weights(int b, const float* __restrict__ sigmas,
                                            const int* __restrict__ steps,
                                            float* wl, float* red) {
    int t = threadIdx.x;
    float sigma = sigmas[steps[b]];
    float radf = floorf(4.0f * sigma + 0.5f);
    if (t < 192) {
        float w = 0.0f;
        if (t < 161) {
            float off = (float)(t - RR);
            if (fabsf(off) <= radf) {
                float z = off / sigma;
                w = expf(-0.5f * z * z);
            }
        }
        wl[t] = w;
    }
    __syncthreads();
    if (t < 64) {
        float s = wl[t] + wl[t + 64] + wl[t + 128];
        #pragma unroll
        for (int o = 32; o > 0; o >>= 1) s += __shfl_down(s, o);
        if (t == 0) red[0] = 1.0f / s;
    }
    __syncthreads();
    float rs = red[0];
    if (t < 161) wl[t] *= rs;
    __syncthreads();
    return (int)radf;
}

// Fused separable blur: block = (sample b, row band [r0, r0+64)).
// Phase V: vertical blur of the band from global input (register window,
//          1-chunk-deep prefetch), result -> LDS T[c][i] (f16, transposed,
//          swizzled). Phase H: horizontal blur reading T rows, write f32 out.
// One barrier between phases; no global intermediate.
__global__ __launch_bounds__(256, 3) void blur_fused(const float* __restrict__ in,
                                                     float* __restrict__ out,
                                                     const float* __restrict__ sigmas,
                                                     const int* __restrict__ steps) {
    __shared__ _Float16 T[WDIM * RB];   // 32 KB: T[c][i] = vblur(x)[r0+i][c]
    __shared__ float wl[192];
    __shared__ float red[1];

    // XCD swizzle: XCD k gets a contiguous sw range -> all 4 bands of a sample
    // (and 64 consecutive samples) share one per-XCD L2 for input halo reuse.
    int bid = blockIdx.x;
    int sw  = (bid & 7) * (NBLK / 8) + (bid >> 3);
    int b   = sw / NBND;
    int r0  = (sw % NBND) * RB;

    int rad = make_weights(b, sigmas, steps, wl, red);
    int nc  = (2 * rad + UCH) / UCH;    // ceil((2*rad+1)/8)

    int wv = threadIdx.x >> 6;          // wave 0..3
    int ln = threadIdx.x & 63;
    const float* inb = in + (size_t)b * WDIM * WDIM;

    // ---------------- Phase V: vertical blur ----------------
    // Wave wv covers band rows i in [16wv, 16wv+16) as two blocks of 8.
    // Lane ln covers cols 4ln..4ln+3 (f32x4: one wave-load = one full row).
    for (int rb = 0; rb < 2; ++rb) {
        int i0 = (wv << 4) + (rb << 3);     // band-local first output row
        int a0 = r0 + i0 - rad;             // window rel 0 -> absolute input row

        f32x4 w15[15], nv[8], acc[8];
        #pragma unroll
        for (int ii = 0; ii < 8; ++ii) acc[ii] = (f32x4)0.0f;
        #pragma unroll
        for (int s = 0; s < 7; ++s)
            w15[s] = *(const f32x4*)(inb + (size_t)reflect(a0 + s) * WDIM + 4 * ln);
        #pragma unroll
        for (int k = 0; k < 8; ++k)
            nv[k] = *(const f32x4*)(inb + (size_t)reflect(a0 + 7 + k) * WDIM + 4 * ln);

        for (int c = 0; c < nc; ++c) {
            #pragma unroll
            for (int k = 0; k < 8; ++k) w15[7 + k] = nv[k];
            // prefetch next chunk's rows (consumed next iteration -> ~1 chunk
            // of FMA hides the L2/HBM latency). Harmless overshoot on last c.
            #pragma unroll
            for (int k = 0; k < 8; ++k)
                nv[k] = *(const f32x4*)(inb + (size_t)reflect(a0 + 8 * (c + 1) + 7 + k) * WDIM + 4 * ln);
            float wreg[UCH];
            #pragma unroll
            for (int t = 0; t < UCH; ++t) wreg[t] = wl[RR - rad + 8 * c + t];
            #pragma unroll
            for (int ii = 0; ii < 8; ++ii) {
                #pragma unroll
                for (int t = 0; t < UCH; ++t)
                    acc[ii] += wreg[t] * w15[ii + t];
            }
            #pragma unroll
            for (int s = 0; s < 7; ++s) w15[s] = w15[s + 8];
        }

        // Transposed f16 store into T: lane ln, k -> T[4ln+k][i0..i0+7] (16B,
        // swizzled -> lanes hit 8 distinct granules = minimal conflict).
        #pragma unroll
        for (int k = 0; k < 4; ++k) {
            int c = 4 * ln + k;
            f16x8 v;
            #pragma unroll
            for (int ii = 0; ii < 8; ++ii) v[ii] = (_Float16)acc[ii][k];
            *(f16x8*)&T[(((c << 6) + i0)) ^ swz(c)] = v;
        }
    }
    __syncthreads();

    // ---------------- Phase H: horizontal blur ----------------
    // out[r0+i][cout] = sum_u w[u] * T[reflect(cout+u)][i].
    // Lane: q = ln>>4 picks a cout-block, lr = ln&15 covers i = 4lr..4lr+3.
    int q  = ln >> 4;
    int lr = ln & 15;
    float* ob = out + (size_t)b * WDIM * WDIM;

    for (int half = 0; half < 2; ++half) {
        int c0 = ((wv << 2) + q + (half << 4)) << 3;   // cout block start
        int a0 = c0 - rad;

        f32x4 w15[15], acc[8];
        #pragma unroll
        for (int ii = 0; ii < 8; ++ii) acc[ii] = (f32x4)0.0f;
        #pragma unroll
        for (int s = 0; s < 7; ++s) {
            int ci = reflect(a0 + s);
            w15[s] = h4_to_f32(*(const f16x4*)&T[(((ci << 6) + 4 * lr)) ^ swz(ci)]);
        }

        for (int c = 0; c < nc; ++c) {
            #pragma unroll
            for (int s = 7; s < 15; ++s) {
                int ci = reflect(a0 + 8 * c + s);
                w15[s] = h4_to_f32(*(const f16x4*)&T[(((ci << 6) + 4 * lr)) ^ swz(ci)]);
            }
            float wreg[UCH];
            #pragma unroll
            for (int t = 0; t < UCH; ++t) wreg[t] = wl[RR - rad + 8 * c + t];
            #pragma unroll
            for (int ii = 0; ii < 8; ++ii) {
                #pragma unroll
                for (int t = 0; t < UCH; ++t)
                    acc[ii] += wreg[t] * w15[ii + t];
            }
            #pragma unroll
            for (int s = 0; s < 7; ++s) w15[s] = w15[s + 8];
        }

        // Store: lane (q,lr), k -> row r0+4lr+k, cols c0..c0+7 (2x f32x4).
        #pragma unroll
        for (int k = 0; k < 4; ++k) {
            int r = r0 + 4 * lr + k;
            f32x4 v0, v1;
            v0[0] = acc[0][k]; v0[1] = acc[1][k]; v0[2] = acc[2][k]; v0[3] = acc[3][k];
            v1[0] = acc[4][k]; v1[1] = acc[5][k]; v1[2] = acc[6][k]; v1[3] = acc[7][k];
            *(f32x4*)(ob + (size_t)r * WDIM + c0)     = v0;
            *(f32x4*)(ob + (size_t)r * WDIM + c0 + 4) = v1;
        }
    }
}

extern "C" void kernel_launch(void* const* d_in, const int* in_sizes, int n_in,
                              void* d_out, int out_size, void* d_ws, size_t ws_size,
                              hipStream_t stream) {
    const float* x     = (const float*)d_in[0];
    const float* sig   = (const float*)d_in[1];
    const int*   steps = (const int*)d_in[2];
    float* out = (float*)d_out;
    (void)d_ws; (void)ws_size;

    blur_fused<<<NBLK, 256, 0, stream>>>(x, out, sig, steps);
}